// Round 15
// baseline (102.477 us; speedup 1.0000x reference)
//
#include <hip/hip_runtime.h>

// B=2, D=64, N=512, H=256, OUT=64
// mid[b] = sum_{c,i} relu( relu(hi[b,i,:]+hcb[b,c,:]) @ w2 + b2 ) @ w3 + N^2*b3
// out = relu(mid @ w4 + b4) @ w5 + b5
//
// big v15: PRODUCER-CONSUMER wave specialization (m114: MFMA-only and VALU-only
// waves co-schedule fully). 256 blocks (1/CU, 8 waves). Block=(b, c-quad cq):
// 64 tiles (32 rows = 4c x 8i, K=256). Waves 0-3 = consumers (1/SIMD): B-frags
// for n-blocks {w, w+4} in 128 regs; per tile 16 ds_read_b128 + 32 MFMA
// (4 chains) + epilogue. Waves 4-7 = producers: global hi/hc loads + relu +
// cvt_pk -> ds_write into a 6-slot ring (96 KB). Flags in LDS, gen-counted.

using f32x16  = __attribute__((ext_vector_type(16))) float;
using short8  = __attribute__((ext_vector_type(8))) short;
using float4v = __attribute__((ext_vector_type(4))) float;

__device__ __forceinline__ short f2bf(float f) {
    unsigned u = __float_as_uint(f);
    unsigned r = u + 0x7FFFu + ((u >> 16) & 1u);   // RNE
    return (short)(r >> 16);
}

__device__ __forceinline__ short8 relu_pack8(float4v lo, float4v hi4) {
#pragma unroll
    for (int e = 0; e < 4; ++e) {
        lo[e]  = fmaxf(lo[e], 0.f);
        hi4[e] = fmaxf(hi4[e], 0.f);
    }
    union { short8 s; unsigned u[4]; } r;
    asm("v_cvt_pk_bf16_f32 %0, %1, %2" : "=v"(r.u[0]) : "v"(lo[0]),  "v"(lo[1]));
    asm("v_cvt_pk_bf16_f32 %0, %1, %2" : "=v"(r.u[1]) : "v"(lo[2]),  "v"(lo[3]));
    asm("v_cvt_pk_bf16_f32 %0, %1, %2" : "=v"(r.u[2]) : "v"(hi4[0]), "v"(hi4[1]));
    asm("v_cvt_pk_bf16_f32 %0, %1, %2" : "=v"(r.u[3]) : "v"(hi4[2]), "v"(hi4[3]));
    return r.s;
}

// ---- prep: blocks [0,256): hi/hcb (4 n-cols per block); [256,512): frag-ordered w2
__global__ __launch_bounds__(256) void prep(const float* __restrict__ in,
                                            const float* __restrict__ w1,
                                            const float* __restrict__ b1,
                                            const float* __restrict__ w2,
                                            float* __restrict__ hi,
                                            float* __restrict__ hcb,
                                            short* __restrict__ bfrag) {
    int tid = threadIdx.x;
    int bidx = blockIdx.x;
    if (bidx < 256) {
        int b = bidx >> 7, n0 = (bidx & 127) * 4;
        __shared__ float xs[4][64];
        {
            int nn = tid >> 6, d = tid & 63;
            xs[nn][d] = in[(size_t)(b * 64 + d) * 512 + n0 + nn];
        }
        __syncthreads();
        float a0[4] = {0.f, 0.f, 0.f, 0.f}, a1[4] = {0.f, 0.f, 0.f, 0.f};
#pragma unroll 8
        for (int d = 0; d < 64; ++d) {
            float wA = w1[d * 256 + tid];
            float wB = w1[(64 + d) * 256 + tid];
#pragma unroll
            for (int nn = 0; nn < 4; ++nn) {
                a0[nn] += xs[nn][d] * wA;
                a1[nn] += xs[nn][d] * wB;
            }
        }
        float bb = b1[tid];
#pragma unroll
        for (int nn = 0; nn < 4; ++nn) {
            size_t o = (size_t)(b * 512 + n0 + nn) * 256 + tid;
            hi[o]  = a0[nn];
            hcb[o] = a1[nn] + bb;
        }
    } else {
        // off = ((n*16+kk)*64 + h*32+col)*8 + j ; value bf16(w2[k][ncol])
        int idx = (bidx - 256) * 256 + tid;        // [0, 65536)
        int k = idx >> 8, ncol = idx & 255;
        int n = ncol >> 5, col = ncol & 31;
        int kk = k >> 4, h = (k >> 3) & 1, j = k & 7;
        int off = (((n * 16 + kk) * 64) + h * 32 + col) * 8 + j;
        bfrag[off] = f2bf(w2[k * 256 + ncol]);
    }
}

// ---- big v15: 256 blocks x 512 threads; ring 96 KB + flags
__global__ __launch_bounds__(512, 1) void big(const float* __restrict__ hi_,
                                              const float* __restrict__ hcb_,
                                              const short8* __restrict__ bfrag,
                                              const float* __restrict__ b2,
                                              float* __restrict__ partials) {
    __shared__ __align__(16) short8 ring[6][1024];   // 6 x 16 KB: [kk][lane]
    __shared__ unsigned ready_f[6];
    __shared__ unsigned done_f[6];

    const int tid = threadIdx.x;                  // 0..511
    const int bid = blockIdx.x;                   // [0,256)
    const int b = bid >> 7, cq = bid & 127;

    if (tid < 6) { ready_f[tid] = 0u; done_f[tid] = 4u; }
    __syncthreads();

    volatile unsigned* vready = ready_f;
    volatile unsigned* vdone  = done_f;

    const int w = tid >> 6, lane = tid & 63;
    const int l31 = lane & 31, h = lane >> 5;

    if (w < 4) {
        // ================= CONSUMER (one per SIMD): n-blocks w, w+4 =================
        short8 bfr0[16], bfr1[16];
#pragma unroll
        for (int kk = 0; kk < 16; ++kk) {
            bfr0[kk] = bfrag[(size_t)((w * 16 + kk) * 64 + lane)];
            bfr1[kk] = bfrag[(size_t)(((w + 4) * 16 + kk) * 64 + lane)];
        }
        const float b2v0 = b2[w * 32 + l31];
        const float b2v1 = b2[(w + 4) * 32 + l31];
        float js0 = 0.f, js1 = 0.f;

#pragma unroll 1
        for (int t = 0; t < 64; ++t) {
            const int s = t % 6;
            while (vready[s] != (unsigned)(t + 1)) __builtin_amdgcn_s_sleep(1);
            const short8* __restrict__ slot = &ring[s][lane];

            f32x16 aA0, aA1, aB0, aB1;    // even/odd-kk chains for n0 / n1
#pragma unroll
            for (int e = 0; e < 16; ++e) { aA0[e] = 0.f; aA1[e] = 0.f; aB0[e] = 0.f; aB1[e] = 0.f; }

            __builtin_amdgcn_s_setprio(1);
#pragma unroll
            for (int kk = 0; kk < 16; kk += 2) {
                short8 a0 = slot[kk * 64];
                short8 a1 = slot[(kk + 1) * 64];
                aA0 = __builtin_amdgcn_mfma_f32_32x32x16_bf16(a0, bfr0[kk],     aA0, 0, 0, 0);
                aB0 = __builtin_amdgcn_mfma_f32_32x32x16_bf16(a0, bfr1[kk],     aB0, 0, 0, 0);
                aA1 = __builtin_amdgcn_mfma_f32_32x32x16_bf16(a1, bfr0[kk + 1], aA1, 0, 0, 0);
                aB1 = __builtin_amdgcn_mfma_f32_32x32x16_bf16(a1, bfr1[kk + 1], aB1, 0, 0, 0);
            }
            __builtin_amdgcn_s_setprio(0);
            if (lane == 0) atomicAdd(&done_f[s], 1u);   // LDS ops in-order: reads done

            float s0a = 0.f, s0b = 0.f, s1a = 0.f, s1b = 0.f;
#pragma unroll
            for (int e = 0; e < 16; e += 2) {
                s0a += fmaxf(aA0[e]     + aA1[e]     + b2v0, 0.f);
                s0b += fmaxf(aA0[e + 1] + aA1[e + 1] + b2v0, 0.f);
                s1a += fmaxf(aB0[e]     + aB1[e]     + b2v1, 0.f);
                s1b += fmaxf(aB0[e + 1] + aB1[e + 1] + b2v1, 0.f);
            }
            js0 += s0a + s0b;
            js1 += s1a + s1b;
        }
        js0 += __shfl_xor(js0, 32);
        js1 += __shfl_xor(js1, 32);
        if (h == 0) {
            partials[((size_t)(b * 256 + w * 32 + l31)) * 128 + cq]       = js0;
            partials[((size_t)(b * 256 + (w + 4) * 32 + l31)) * 128 + cq] = js1;
        }
    } else {
        // ================= PRODUCER pw: tiles t = pw, pw+4, ... =================
        const int pw = w - 4;
        const int ip = l31 & 7, cq4 = l31 >> 3;   // tile row l31 = cq4*8 + ip
        const float* __restrict__ hrowb = hi_ + (size_t)b * 131072
                                        + (size_t)ip * 256 + h * 8;
        const float* __restrict__ crow  = hcb_ + (size_t)b * 131072
                                        + (size_t)(cq * 4 + cq4) * 256 + h * 8;
#pragma unroll 1
        for (int t = pw; t < 64; t += 4) {
            const int s = t % 6;
            while (vdone[s] != 4u) __builtin_amdgcn_s_sleep(1);
            if (lane == 0) vdone[s] = 0u;
            const float* __restrict__ hrow = hrowb + (size_t)t * (8 * 256);
            short8* __restrict__ slot = &ring[s][lane];
#pragma unroll
            for (int kk = 0; kk < 16; ++kk) {
                float4v x0 = *reinterpret_cast<const float4v*>(hrow + kk * 16);
                float4v x1 = *reinterpret_cast<const float4v*>(hrow + kk * 16 + 4);
                float4v c0 = *reinterpret_cast<const float4v*>(crow + kk * 16);
                float4v c1 = *reinterpret_cast<const float4v*>(crow + kk * 16 + 4);
                slot[kk * 64] = relu_pack8(x0 + c0, x1 + c1);
            }
            asm volatile("s_waitcnt lgkmcnt(0)" ::: "memory");
            if (lane == 0) vready[s] = (unsigned)(t + 1);
        }
    }
}

// ---- reduceK: 512 blocks (one per (b,col)) x 128 thr; sums 128 slots
__global__ __launch_bounds__(128) void reduceK(const float* __restrict__ partials,
                                               float* __restrict__ su_g) {
    int tid = threadIdx.x, blk = blockIdx.x;      // blk = b*256 + col
    float s = partials[(size_t)blk * 128 + tid];
#pragma unroll
    for (int d = 1; d < 64; d <<= 1) s += __shfl_xor(s, d);
    __shared__ float ws[2];
    if ((tid & 63) == 0) ws[tid >> 6] = s;
    __syncthreads();
    if (tid == 0) su_g[blk] = ws[0] + ws[1];
}

// ---- final tail MLP (reads 512-float su_g), 512 thr
__global__ __launch_bounds__(512) void finalK(const float* __restrict__ su_g,
                                              const float* __restrict__ w3,
                                              const float* __restrict__ b3,
                                              const float* __restrict__ w4,
                                              const float* __restrict__ b4,
                                              const float* __restrict__ w5,
                                              const float* __restrict__ b5,
                                              float* __restrict__ out) {
    __shared__ float su[2][256], mid[2][256], o[2][256];
    int tid = threadIdx.x;
    int b = tid >> 8, c = tid & 255;
    su[b][c] = su_g[b * 256 + c];
    __syncthreads();
    float m = 262144.0f * b3[c];
    for (int k = 0; k < 256; ++k) m += su[b][k] * w3[k * 256 + c];
    mid[b][c] = m;
    __syncthreads();
    float ov = b4[c];
    for (int k = 0; k < 256; ++k) ov += mid[b][k] * w4[k * 256 + c];
    o[b][c] = fmaxf(ov, 0.f);
    __syncthreads();
    if (c < 64) {
        float rr = b5[c];
        for (int k = 0; k < 256; ++k) rr += o[b][k] * w5[k * 64 + c];
        out[b * 64 + c] = rr;
    }
}

extern "C" void kernel_launch(void* const* d_in, const int* in_sizes, int n_in,
                              void* d_out, int out_size, void* d_ws, size_t ws_size,
                              hipStream_t stream) {
    const float* in = (const float*)d_in[0];
    const float* w1 = (const float*)d_in[1];
    const float* b1 = (const float*)d_in[2];
    const float* w2 = (const float*)d_in[3];
    const float* b2 = (const float*)d_in[4];
    const float* w3 = (const float*)d_in[5];
    const float* b3 = (const float*)d_in[6];
    const float* w4 = (const float*)d_in[7];
    const float* b4 = (const float*)d_in[8];
    const float* w5 = (const float*)d_in[9];
    const float* b5 = (const float*)d_in[10];
    float* out = (float*)d_out;

    char* ws = (char*)d_ws;
    float* hi       = (float*)(ws);                                   // 1 MB
    float* hcb      = (float*)(ws + (1u << 20));                      // 1 MB
    short* bfrag    = (short*)(ws + (2u << 20));                      // 128 KB
    float* partials = (float*)(ws + (2u << 20) + (1u << 18));         // 256 KB (2x256x128)
    float* su_g     = (float*)(ws + (2u << 20) + (2u << 18));         // 2 KB

    prep<<<512, 256, 0, stream>>>(in, w1, b1, w2, hi, hcb, bfrag);
    big<<<256, 512, 0, stream>>>(hi, hcb, (const short8*)bfrag, b2, partials);
    reduceK<<<512, 128, 0, stream>>>(partials, su_g);
    finalK<<<1, 512, 0, stream>>>(su_g, w3, b3, w4, b4, w5, b5, out);
}